// Round 16
// baseline (173.787 us; speedup 1.0000x reference)
//
#include <hip/hip_runtime.h>
#include <stdint.h>

typedef unsigned int u32;
typedef unsigned long long u64;
typedef unsigned short u16;
typedef float f32x4 __attribute__((ext_vector_type(4)));
typedef float f32x2 __attribute__((ext_vector_type(2)));
typedef short short8 __attribute__((ext_vector_type(8)));
typedef unsigned int u32x2 __attribute__((ext_vector_type(2)));
typedef unsigned int u32x4 __attribute__((ext_vector_type(4)));

#define HID  128
#define MT   32        // batch rows per WG
#define NWG  256       // 1 WG/CU -- deadlock-proof envelope
#define NTHR 256       // 4 waves (r14)
#define LD   136       // LDS plane stride in u16 (272B rows)

// 16B-slot swizzle: slot s of row r lives at physical slot (s + 2r) & 15.
// Applied identically at every write and read of Ahi -> per-row bijective.
#define SWEL(s, row) ((((s) + 2*(row)) & 15) * 8)

// ---- ws byte offsets (r13 layout) ----
#define OFF_ROOT  0        // 56 roots, 64B stride (fused value<<10 | count)
#define OFF_LEAF  4096     // 56 x 16 leaves, 64B stride
#define OFF_WPACK 61440    // 644 f32: W1(256) b1(128) b2(128) b3(128) b4(2)
#define OFF_W2TH  65536    // 128x128 bf16 [n][k]
#define OFF_W3TH  98304

constexpr float CA21 = (float)(1.0/5.0);
constexpr float CA31 = (float)(3.0/40.0),   CA32 = (float)(9.0/40.0);
constexpr float CA41 = (float)(44.0/45.0),  CA42 = (float)(-56.0/15.0), CA43 = (float)(32.0/9.0);
constexpr float CA51 = (float)(19372.0/6561.0), CA52 = (float)(-25360.0/2187.0);
constexpr float CA53 = (float)(64448.0/6561.0), CA54 = (float)(-212.0/729.0);
constexpr float CA61 = (float)(9017.0/3168.0),  CA62 = (float)(-355.0/33.0);
constexpr float CA63 = (float)(46732.0/5247.0), CA64 = (float)(49.0/176.0), CA65 = (float)(-5103.0/18656.0);
constexpr float CB1 = (float)(35.0/384.0), CB3 = (float)(500.0/1113.0), CB4 = (float)(125.0/192.0);
constexpr float CB5 = (float)(-2187.0/6784.0), CB6 = (float)(11.0/84.0);
constexpr float CE1 = (float)(35.0/384.0 - 5179.0/57600.0);
constexpr float CE3 = (float)(500.0/1113.0 - 7571.0/16695.0);
constexpr float CE4 = (float)(125.0/192.0 - 393.0/640.0);
constexpr float CE5 = (float)(-2187.0/6784.0 + 92097.0/339200.0);
constexpr float CE6 = (float)(11.0/84.0 - 187.0/2100.0);
constexpr float CE7 = (float)(-1.0/40.0);

template<int N> struct IC { static constexpr int v = N; };

__device__ __forceinline__ u16 f2bf(float x) {
  u32 u = __builtin_bit_cast(u32, x);
  u32 r = (u + 0x7FFFu + ((u >> 16) & 1u)) >> 16;
  return (u16)r;
}
__device__ __forceinline__ float eluf(float x) {
  return x > 0.f ? x : (__expf(x) - 1.f);
}
// v_cvt_pk_bf16_f32: dst[15:0]=bf16(a), dst[31:16]=bf16(b) (RNE)
__device__ __forceinline__ u32 cvtpk(float a, float b) {
  u32 r; asm("v_cvt_pk_bf16_f32 %0, %1, %2" : "=v"(r) : "v"(a), "v"(b)); return r;
}

// ---------------------------------------------------------------------------
// Prologue
// ---------------------------------------------------------------------------
__global__ void prologue(const float* __restrict__ x0, const float* __restrict__ t,
                         const float* __restrict__ W1, const float* __restrict__ b1,
                         const float* __restrict__ W2, const float* __restrict__ b2,
                         const float* __restrict__ W3, const float* __restrict__ b3,
                         const float* __restrict__ W4, const float* __restrict__ b4,
                         float* __restrict__ ws, float* __restrict__ out)
{
  int gid = blockIdx.x * blockDim.x + threadIdx.x;   // 64*256 = 16384
  out[gid] = x0[gid];
  {
    int k = gid >> 7, j = gid & 127;
    u16* w2th = (u16*)((char*)ws + OFF_W2TH);
    u16* w3th = (u16*)((char*)ws + OFF_W3TH);
    w2th[j*HID + k] = f2bf(W2[gid]);
    w3th[j*HID + k] = f2bf(W3[gid]);
  }
  float* wp = ws + OFF_WPACK/4;
  if (gid < 256) wp[gid] = W1[gid];
  if (gid < 128) {
    wp[256 + gid] = b1[gid];
    wp[384 + gid] = b2[gid];
    wp[512 + gid] = b3[gid];
  }
  if (gid < 2)  wp[640 + gid] = b4[gid];
  if (gid < 15360) ((u32*)ws)[gid] = 0u;   // roots + leaves zeroed
}

// ---------------------------------------------------------------------------
// Persistent solver: 256 WGs x 256 threads (4 waves), 1 WG/CU.
// r15 structure (Ahi slot swizzle + Wsm1 per-jc W1 layout) with the
// Wsm1 init bug fixed: strided fill (NTHR=256 threads, 384 entries).
// ---------------------------------------------------------------------------
__global__ __launch_bounds__(NTHR, 2)
void solver(const float* __restrict__ x0, const float* __restrict__ t_arr,
            const float* __restrict__ W4g, float* __restrict__ ws,
            float* __restrict__ out)
{
  const int tid  = threadIdx.x;
  const int wg   = blockIdx.x;
  const int lane = tid & 63;
  const int wv   = tid >> 6;       // 4 waves
  const int nl   = lane & 15;      // MFMA fragment index
  const int g    = lane >> 4;      // k-group
  const int m    = tid >> 3;       // owned batch row (32 rows, 8 thr each)
  const int jc   = tid & 7;        // col-chunk within row (16 cols each)

  __shared__ __align__(16) u16 Ahi[2][MT][LD];
  __shared__ __align__(16) float Wsm[644];
  __shared__ __align__(16) float Wsm1[8][52];     // [jc]: w0[16] w1[16] b1[16] pad4
  __shared__ __align__(16) float kSm[6][MT][2];   // k mirrors for err pass
  __shared__ __align__(16) float yLm[MT][2];
  __shared__ __align__(16) float y5m[MT][2];
  __shared__ __align__(16) float pD[4][MT][2];
  __shared__ u32 flagL;
  __shared__ u32 bcFl;
  __shared__ float bcHl;

  // ---- one-time setup ----
  {
    const float* wp = ws + OFF_WPACK/4;
    Wsm[tid] = wp[tid];
    Wsm[256 + tid] = wp[256 + tid];
    if (tid < 132) Wsm[512 + tid] = wp[512 + tid];
    // W1/b1 per-jc layout: Wsm1[grp][0..15]=W1row0, [16..31]=W1row1, [32..47]=b1
    for (int i = tid; i < 384; i += NTHR) {         // r15 bug: was `if (tid<384)` with 256 thr
      int grp = i / 48, idx = i - grp*48;
      float v;
      if (idx < 16)       v = wp[grp*16 + idx];
      else if (idx < 32)  v = wp[128 + grp*16 + (idx - 16)];
      else                v = wp[256 + grp*16 + (idx - 32)];
      Wsm1[grp][idx] = v;
    }
  }
  if (tid == 0) flagL = 0u;
  float y0r = x0[wg*64 + m*2 + 0];
  float y1r = x0[wg*64 + m*2 + 1];
  if (jc == 0) { yLm[m][0] = y0r; yLm[m][1] = y1r; }

  // resident W2/W3 fragments: 2 n-tiles per wave
  const u16* w2th = (const u16*)((const char*)ws + OFF_W2TH);
  const u16* w3th = (const u16*)((const char*)ws + OFF_W3TH);
  short8 W2H[2][4], W3H[2][4];
#pragma unroll
  for (int nt = 0; nt < 2; ++nt) {
    const int nglob = (wv*2 + nt)*16 + nl;
#pragma unroll
    for (int ks = 0; ks < 4; ++ks) {
      int off = nglob*HID + ks*32 + g*8;
      W2H[nt][ks] = *(const short8*)(w2th + off);
      W3H[nt][ks] = *(const short8*)(w3th + off);
    }
  }
  // per-lane W4 slices
  float w4c[2][4][2];
#pragma unroll
  for (int nt = 0; nt < 2; ++nt)
#pragma unroll
    for (int r = 0; r < 4; ++r) {
      int n = (wv*2 + nt)*16 + g*4 + r;
      w4c[nt][r][0] = W4g[n*2 + 0];
      w4c[nt][r][1] = W4g[n*2 + 1];
    }
  __syncthreads();
  f32x4 bv2[2], bv3[2];
#pragma unroll
  for (int nt = 0; nt < 2; ++nt) {
    bv2[nt] = *(const f32x4*)&Wsm[384 + (wv*2 + nt)*16 + g*4];
    bv3[nt] = *(const f32x4*)&Wsm[512 + (wv*2 + nt)*16 + g*4];
  }
  const float b40 = Wsm[640], b41 = Wsm[641];

  float khv[6][2];      // k1..k6 (all indices compile-time)
  float y5r0 = 0.f, y5r1 = 0.f;

  float h = 0.5f * (t_arr[1] - t_arr[0]);
  float heff = h;

  // ---- phase A: register stage-combine + L1 (16 cols/thread) -> plane0 ----
  auto phaseA = [&](auto SC) {
    constexpr int S = decltype(SC)::v;
    float ys0, ys1;
    if constexpr (S == 1) {
      ys0 = y0r; ys1 = y1r;
    } else {
      float kp0, kp1;
      if constexpr (S == 2) {
        kp0 = khv[0][0]; kp1 = khv[0][1];
      } else {
        kp0 = b40; kp1 = b41;
#pragma unroll
        for (int w = 0; w < 4; ++w) {
          f32x2 p = *(const f32x2*)&pD[w][m][0];
          kp0 += p[0]; kp1 += p[1];
        }
        khv[S-2][0] = kp0; khv[S-2][1] = kp1;
        if constexpr (S >= 4) {
          if (jc == 0) { kSm[S-2][m][0] = kp0; kSm[S-2][m][1] = kp1; }
        }
      }
      if constexpr (S == 2) {
        ys0 = fmaf(heff, CA21*kp0, y0r);
        ys1 = fmaf(heff, CA21*kp1, y1r);
      } else if constexpr (S == 3) {
        ys0 = fmaf(heff, CA31*khv[0][0] + CA32*kp0, y0r);
        ys1 = fmaf(heff, CA31*khv[0][1] + CA32*kp1, y1r);
      } else if constexpr (S == 4) {
        ys0 = fmaf(heff, CA41*khv[0][0] + CA42*khv[1][0] + CA43*kp0, y0r);
        ys1 = fmaf(heff, CA41*khv[0][1] + CA42*khv[1][1] + CA43*kp1, y1r);
      } else if constexpr (S == 5) {
        ys0 = fmaf(heff, CA51*khv[0][0] + CA52*khv[1][0] + CA53*khv[2][0] + CA54*kp0, y0r);
        ys1 = fmaf(heff, CA51*khv[0][1] + CA52*khv[1][1] + CA53*khv[2][1] + CA54*kp1, y1r);
      } else if constexpr (S == 6) {
        ys0 = fmaf(heff, CA61*khv[0][0] + CA62*khv[1][0] + CA63*khv[2][0] + CA64*khv[3][0] + CA65*kp0, y0r);
        ys1 = fmaf(heff, CA61*khv[0][1] + CA62*khv[1][1] + CA63*khv[2][1] + CA64*khv[3][1] + CA65*kp1, y1r);
      } else {  // S == 7: y5
        ys0 = fmaf(heff, CB1*khv[0][0] + CB3*khv[2][0] + CB4*khv[3][0] + CB5*khv[4][0] + CB6*kp0, y0r);
        ys1 = fmaf(heff, CB1*khv[0][1] + CB3*khv[2][1] + CB4*khv[3][1] + CB5*khv[4][1] + CB6*kp1, y1r);
        y5r0 = ys0; y5r1 = ys1;
        if (jc == 0) { y5m[m][0] = ys0; y5m[m][1] = ys1; }
      }
    }
    // L1: 16 cols per thread, single-bf16 pack -> plane0 (swizzled slots)
    const float* wj = &Wsm1[jc][0];
    u32 hp[8];
#pragma unroll
    for (int b = 0; b < 4; ++b) {
      f32x4 w0 = *(const f32x4*)&wj[b*4];
      f32x4 w1 = *(const f32x4*)&wj[16 + b*4];
      f32x4 bb = *(const f32x4*)&wj[32 + b*4];
      float v0 = eluf(fmaf(ys1, w1[0], fmaf(ys0, w0[0], bb[0])));
      float v1 = eluf(fmaf(ys1, w1[1], fmaf(ys0, w0[1], bb[1])));
      float v2 = eluf(fmaf(ys1, w1[2], fmaf(ys0, w0[2], bb[2])));
      float v3 = eluf(fmaf(ys1, w1[3], fmaf(ys0, w0[3], bb[3])));
      hp[b*2 + 0] = cvtpk(v0, v1);
      hp[b*2 + 1] = cvtpk(v2, v3);
    }
    u32x4 pa = {hp[0], hp[1], hp[2], hp[3]};
    u32x4 pb = {hp[4], hp[5], hp[6], hp[7]};
    *(u32x4*)&Ahi[0][m][SWEL(2*jc,     m)] = pa;
    *(u32x4*)&Ahi[0][m][SWEL(2*jc + 1, m)] = pb;
  };

  // ---- L2: plane0 -> plane1 (16 MFMAs: 2 mt x 2 nt x 4 ks) ----
  auto mmL2 = [&]() {
    f32x4 acc[2][2];
#pragma unroll
    for (int mt = 0; mt < 2; ++mt)
#pragma unroll
      for (int nt = 0; nt < 2; ++nt) acc[mt][nt] = bv2[nt];
#pragma unroll
    for (int ks = 0; ks < 4; ++ks)
#pragma unroll
      for (int mt = 0; mt < 2; ++mt) {
        const int row = mt*16 + nl;
        short8 bh = *(const short8*)&Ahi[0][row][SWEL(ks*4 + g, row)];
#pragma unroll
        for (int nt = 0; nt < 2; ++nt)
          acc[mt][nt] = __builtin_amdgcn_mfma_f32_16x16x32_bf16(W2H[nt][ks], bh, acc[mt][nt], 0, 0, 0);
      }
#pragma unroll
    for (int mt = 0; mt < 2; ++mt)
#pragma unroll
      for (int nt = 0; nt < 2; ++nt) {
        float v0 = eluf(acc[mt][nt][0]);
        float v1 = eluf(acc[mt][nt][1]);
        float v2 = eluf(acc[mt][nt][2]);
        float v3 = eluf(acc[mt][nt][3]);
        u32x2 hp = {cvtpk(v0, v1), cvtpk(v2, v3)};
        const int row = mt*16 + nl;
        const int sl = ((wv*2 + nt)*2 + (g >> 1) + 2*row) & 15;
        *(u32x2*)&Ahi[1][row][sl*8 + (g & 1)*4] = hp;
      }
  };

  // ---- L3 + fused L4 dot -> pD ----
  auto mmL3 = [&]() {
    f32x4 acc[2][2];
#pragma unroll
    for (int mt = 0; mt < 2; ++mt)
#pragma unroll
      for (int nt = 0; nt < 2; ++nt) acc[mt][nt] = bv3[nt];
#pragma unroll
    for (int ks = 0; ks < 4; ++ks)
#pragma unroll
      for (int mt = 0; mt < 2; ++mt) {
        const int row = mt*16 + nl;
        short8 bh = *(const short8*)&Ahi[1][row][SWEL(ks*4 + g, row)];
#pragma unroll
        for (int nt = 0; nt < 2; ++nt)
          acc[mt][nt] = __builtin_amdgcn_mfma_f32_16x16x32_bf16(W3H[nt][ks], bh, acc[mt][nt], 0, 0, 0);
      }
#pragma unroll
    for (int mt = 0; mt < 2; ++mt) {
      float p0 = 0.f, p1 = 0.f;
#pragma unroll
      for (int nt = 0; nt < 2; ++nt)
#pragma unroll
        for (int r = 0; r < 4; ++r) {
          float v = eluf(acc[mt][nt][r]);
          p0 = fmaf(v, w4c[nt][r][0], p0);
          p1 = fmaf(v, w4c[nt][r][1], p1);
        }
      p0 += __shfl_xor(p0, 16); p0 += __shfl_xor(p0, 32);
      p1 += __shfl_xor(p1, 16); p1 += __shfl_xor(p1, 32);
      if (lane < 16) {
        f32x2 pp = {p0, p1};
        *(f32x2*)&pD[wv][mt*16 + lane][0] = pp;
      }
    }
  };

  // ---- main adaptive loop ----
  for (int iv = 0; iv < 7; ++iv) {
    const float t1 = t_arr[iv + 1];
    float tc = t_arr[iv];
    for (int s = 0; s < 8; ++s) {
      const int step = iv*8 + s;
      float rem = t1 - tc;
      if (rem <= 1e-9f) break;          // globally uniform
      heff = fminf(h, rem);

      if (iv == 0 && s == 0) {          // fresh k1 eval
        phaseA(IC<1>{}); __syncthreads();
        mmL2(); __syncthreads();
        mmL3(); __syncthreads();
        float kp0 = b40, kp1 = b41;
#pragma unroll
        for (int w = 0; w < 4; ++w) {
          f32x2 p = *(const f32x2*)&pD[w][m][0];
          kp0 += p[0]; kp1 += p[1];
        }
        khv[0][0] = kp0; khv[0][1] = kp1;
        if (jc == 0) { kSm[0][m][0] = kp0; kSm[0][m][1] = kp1; }
      }
      phaseA(IC<2>{}); __syncthreads(); mmL2(); __syncthreads(); mmL3(); __syncthreads();
      phaseA(IC<3>{}); __syncthreads(); mmL2(); __syncthreads(); mmL3(); __syncthreads();
      phaseA(IC<4>{}); __syncthreads(); mmL2(); __syncthreads(); mmL3(); __syncthreads();
      phaseA(IC<5>{}); __syncthreads(); mmL2(); __syncthreads(); mmL3(); __syncthreads();
      phaseA(IC<6>{}); __syncthreads(); mmL2(); __syncthreads(); mmL3(); __syncthreads();
      phaseA(IC<7>{}); __syncthreads(); mmL2(); __syncthreads(); mmL3(); __syncthreads();
      // pD holds k7 partials

      // ---- error (wave 0: 64 lanes = 32 rows x 2 dims) + tree publish ----
      if (wv == 0) {
        int em = lane >> 1, ec = lane & 1;
        float kp = ec ? b41 : b40;
#pragma unroll
        for (int w = 0; w < 4; ++w) kp += pD[w][em][ec];
        float e = heff * (CE1*kSm[0][em][ec] + CE3*kSm[2][em][ec] + CE4*kSm[3][em][ec]
                        + CE5*kSm[4][em][ec] + CE6*kSm[5][em][ec] + CE7*kp);
        float tol = 1e-4f + 1e-3f * fmaxf(fabsf(yLm[em][ec]), fabsf(y5m[em][ec]));
        float rr = e / tol;
        float es = rr * rr;
#pragma unroll
        for (int mk = 1; mk < 64; mk <<= 1) es += __shfl_xor(es, mk);
        if (lane == 0) {
          if (!(es < 1e9f)) es = 1e9f;                // clamp + NaN guard
          u64 q = (u64)(es * 1024.0f);                // fixed-point x2^10
          u64 add = (q << 10) | 1ULL;
          u64* leaf = (u64*)((char*)ws + OFF_LEAF + ((size_t)step*16 + (wg & 15))*64);
          u64 old = __hip_atomic_fetch_add(leaf, add, __ATOMIC_ACQ_REL, __HIP_MEMORY_SCOPE_AGENT);
          if ((old & 0x3FFULL) == 15ULL) {            // 16th arrival forwards to root
            u64 tot = old + add;
            u64 radd = ((tot >> 10) << 10) | 1ULL;
            u64* rootp = (u64*)((char*)ws + OFF_ROOT + (size_t)step*64);
            __hip_atomic_fetch_add(rootp, radd, __ATOMIC_ACQ_REL, __HIP_MEMORY_SCOPE_AGENT);
          }
        }
      }
      // all threads: FSAL k7 (overlaps the poll)
      float k7p0 = b40, k7p1 = b41;
#pragma unroll
      for (int w = 0; w < 4; ++w) {
        f32x2 p = *(const f32x2*)&pD[w][m][0];
        k7p0 += p[0]; k7p1 += p[1];
      }
      // tid0 polls global root, publishes via LDS flag (no barrier)
      if (tid == 0) {
        u64* rootp = (u64*)((char*)ws + OFF_ROOT + (size_t)step*64);
        u64 v;
        while (((v = __hip_atomic_load(rootp, __ATOMIC_ACQUIRE, __HIP_MEMORY_SCOPE_AGENT)) & 0x3FFULL) != 16ULL)
          __builtin_amdgcn_s_sleep(1);
        float sum = (float)(v >> 10) * (1.0f/1024.0f);
        float err_norm = sqrtf(sum * (1.0f/16384.f));
        bool acc = (err_norm <= 1.0f);
        float factor = fminf(10.f, fmaxf(0.2f, 0.9f * powf(fmaxf(err_norm, 1e-10f), -0.2f)));
        bcFl = acc ? 1u : 0u;
        bcHl = heff * factor;
        __hip_atomic_store(&flagL, (u32)(step + 1), __ATOMIC_RELEASE, __HIP_MEMORY_SCOPE_WORKGROUP);
      }
      while (__hip_atomic_load(&flagL, __ATOMIC_ACQUIRE, __HIP_MEMORY_SCOPE_WORKGROUP) != (u32)(step + 1))
        __builtin_amdgcn_s_sleep(1);
      {
        bool acc = bcFl != 0u;
        if (acc) {
          y0r = y5r0; y1r = y5r1;
          khv[0][0] = k7p0; khv[0][1] = k7p1;        // FSAL: k1 <- k7
          if (jc == 0) {
            kSm[0][m][0] = k7p0; kSm[0][m][1] = k7p1;
            yLm[m][0] = y5r0;    yLm[m][1] = y5r1;
          }
          tc += heff;
        }
        h = bcHl;
      }
    }
    if (jc == 0) {
      f32x2 yo = {y0r, y1r};
      *(f32x2*)&out[(size_t)(iv + 1) * 16384 + wg*64 + m*2] = yo;
    }
  }
}

extern "C" void kernel_launch(void* const* d_in, const int* in_sizes, int n_in,
                              void* d_out, int out_size, void* d_ws, size_t ws_size,
                              hipStream_t stream)
{
  const float* x0 = (const float*)d_in[0];
  const float* t  = (const float*)d_in[1];
  const float* W1 = (const float*)d_in[2];
  const float* b1 = (const float*)d_in[3];
  const float* W2 = (const float*)d_in[4];
  const float* b2 = (const float*)d_in[5];
  const float* W3 = (const float*)d_in[6];
  const float* b3 = (const float*)d_in[7];
  const float* W4 = (const float*)d_in[8];
  const float* b4 = (const float*)d_in[9];
  float* out = (float*)d_out;
  float* ws  = (float*)d_ws;

  prologue<<<64, 256, 0, stream>>>(x0, t, W1, b1, W2, b2, W3, b3, W4, b4, ws, out);
  solver<<<NWG, NTHR, 0, stream>>>(x0, t, W4, ws, out);
}